// Round 1
// baseline (756.903 us; speedup 1.0000x reference)
//
#include <hip/hip_runtime.h>

typedef short bx8 __attribute__((ext_vector_type(8)));
typedef unsigned short ux4 __attribute__((ext_vector_type(4)));
typedef float fx4 __attribute__((ext_vector_type(4)));

#define INV 0.08838834764831843f
#define LP 136           // padded LDS row length in bf16 elems (mult of 8 for b128 alignment)
#define TR 16            // rows per tile
#define NROWS 200000
#define NT (NROWS / TR)  // 12500 tiles
#define NTHREADS 640     // 10 waves
#define NBLOCKS 512      // 2 blocks/CU (was 256 = 1/CU)

__device__ __forceinline__ unsigned short f2bf(float f) {
  unsigned u = __builtin_bit_cast(unsigned, f);
  u += 0x7FFFu + ((u >> 16) & 1u);   // RNE
  return (unsigned short)(u >> 16);
}
__device__ __forceinline__ float bf2f(unsigned short h) {
  unsigned u = ((unsigned)h) << 16;
  return __builtin_bit_cast(float, u);
}
__device__ __forceinline__ float sigm(float z) { return 1.0f / (1.0f + __expf(-z)); }

// Transposed-MFMA fused MLP.
// R1 change vs baseline: 2 blocks/CU for latency overlap.
//   - __launch_bounds__(640,5): VGPR cap 512/5=102 so two 10-wave blocks co-reside.
//   - dropped pf_* prefetch regs (-16 VGPR): inter-block overlap hides HBM latency.
//   - W2 fragments moved to LDS (-16 VGPR): built once, conflict-free b128 reads in D.
// per tile: [load+cvt->X] B1 [L1; gates->GS] B2 [act/gv->ACT] B3 [L2 from ACT; store]
__global__ __launch_bounds__(NTHREADS, 5) void nlr_kernel(
    const float* __restrict__ x, const float* __restrict__ w1_s,
    const float* __restrict__ w1_v, const float* __restrict__ w2_s,
    const float* __restrict__ w2_v, float* __restrict__ out) {
  __shared__ short lds[9 * TR * LP + 4 * 4 * 64 * 8];  // X(4) + ACT(4) + GS + W2L = 55552 B
  short* X = lds;                      // groups: s, v0, v1, v2  each [TR][LP]
  short* ACT = lds + 4 * TR * LP;      // groups: act_s, gv0, gv1, gv2
  short* GS = lds + 8 * TR * LP;       // gates [TR][LP-stride]
  short* W2L = lds + 9 * TR * LP;      // W2 fragments [w][kb][lane][8]

  const int tid = threadIdx.x;
  const int w = tid >> 6;
  const int lane = tid & 63;
  const int quad = lane >> 4;
  const int c16 = lane & 15;
  const int mrow0 = quad * 8;

  // ---- staging role constants ----
  const bool hasS = tid < 512;
  const bool hasV = (tid < 384) || (tid >= 512);
  const int sn = tid >> 5, sch = tid & 31;                  // s: row, float4-chunk
  const int vu = (tid < 384) ? (tid + 128) : (tid - 512);   // v chunk id
  const int vn = vu >> 5, vch = vu & 31;                    // v: row, 12-float chunk

  // ---- build layer-1 weight A-fragments (once, registers: 64 VGPR) ----
  bx8 Wf[4][4];  // [jjb][kb]
  if (w < 4) {   // s-waves: h_s cols [w*64, w*64+64)
#pragma unroll
    for (int jjb = 0; jjb < 4; ++jjb) {
      const int col = (w * 4 + jjb) * 16 + c16;
#pragma unroll
      for (int kb = 0; kb < 4; ++kb) {
        bx8 f;
#pragma unroll
        for (int jj = 0; jj < 8; ++jj)
          f[jj] = (short)f2bf(w1_s[(kb * 32 + mrow0 + jj) * 256 + col]);
        Wf[jjb][kb] = f;
      }
    }
  } else {       // v-waves: c = (w-4)>>1, half = (w-4)&1
    const int half = (w - 4) & 1;
#pragma unroll
    for (int jjb = 0; jjb < 4; ++jjb) {
      const int col = (half * 4 + jjb) * 16 + c16;
#pragma unroll
      for (int kb = 0; kb < 4; ++kb) {
        bx8 f;
#pragma unroll
        for (int jj = 0; jj < 8; ++jj)
          f[jj] = (short)f2bf(w1_v[(kb * 32 + mrow0 + jj) * 128 + col]);
        Wf[jjb][kb] = f;
      }
    }
  }

  // ---- build layer-2 weight fragments into LDS (once; waves 0-3 only) ----
  if (w < 4) {
    const float* w2 = (w == 0) ? w2_s : w2_v;
#pragma unroll
    for (int kb = 0; kb < 4; ++kb) {
      bx8 f;
#pragma unroll
      for (int jj = 0; jj < 8; ++jj)
        f[jj] = (short)f2bf(w2[(kb * 32 + mrow0 + jj) * 16 + c16]);
      *(bx8*)(W2L + ((w * 4 + kb) * 64 + lane) * 8) = f;
    }
  }
  // (first-iteration B1/B2/B3 barriers order W2L writes before any phase-D read)

  int tile = blockIdx.x;
  while (tile < NT) {
    // ---- phase A: load + convert -> X staging (latency hidden by sibling block) ----
    {
      const float* xb = x + (size_t)tile * (TR * 512);
      if (hasS) {
        const fx4 sv = *(const fx4*)(xb + sn * 512 + sch * 4);
        ux4 p = {f2bf(sv[0]), f2bf(sv[1]), f2bf(sv[2]), f2bf(sv[3])};
        *(ux4*)(X + sn * LP + sch * 4) = p;
      }
      if (hasV) {
        const float* bp = xb + vn * 512 + 128 + vch * 12;
        const fx4 va = *(const fx4*)bp;
        const fx4 vb = *(const fx4*)(bp + 4);
        const fx4 vc = *(const fx4*)(bp + 8);
        // i = 3m + c ; chunk covers m = vch*4 .. vch*4+3
        ux4 p0 = {f2bf(va[0]), f2bf(va[3]), f2bf(vb[2]), f2bf(vc[1])};
        ux4 p1 = {f2bf(va[1]), f2bf(vb[0]), f2bf(vb[3]), f2bf(vc[2])};
        ux4 p2 = {f2bf(va[2]), f2bf(vb[1]), f2bf(vc[0]), f2bf(vc[3])};
        *(ux4*)(X + 1 * TR * LP + vn * LP + vch * 4) = p0;
        *(ux4*)(X + 2 * TR * LP + vn * LP + vch * 4) = p1;
        *(ux4*)(X + 3 * TR * LP + vn * LP + vch * 4) = p2;
      }
    }
    __syncthreads();  // B1: X visible; prior-iter ACT/GS reads done

    // ---- phase B: layer 1 (all 10 waves), gates -> GS (waves 2,3) ----
    fx4 acc[4];
    {
      const short* src = (w < 4) ? X : (X + (1 + ((w - 4) >> 1)) * TR * LP);
      bx8 B[4];
      const int rbase = c16 * LP + mrow0;
#pragma unroll
      for (int kb = 0; kb < 4; ++kb) B[kb] = *(const bx8*)(src + rbase + kb * 32);
#pragma unroll
      for (int jjb = 0; jjb < 4; ++jjb) {
        fx4 a = {0.f, 0.f, 0.f, 0.f};
#pragma unroll
        for (int kb = 0; kb < 4; ++kb)
          a = __builtin_amdgcn_mfma_f32_16x16x32_bf16(Wf[jjb][kb], B[kb], a, 0, 0, 0);
        acc[jjb] = a;
      }
    }
    if (w == 2 || w == 3) {  // gate cols 128..255 -> sigmoid -> GS
#pragma unroll
      for (int jjb = 0; jjb < 4; ++jjb) {
        const int jb = w * 4 + jjb;  // 8..15
        ux4 p;
#pragma unroll
        for (int r = 0; r < 4; ++r) p[r] = f2bf(sigm(acc[jjb][r] * INV));
        *(ux4*)(GS + c16 * LP + (jb - 8) * 16 + quad * 4) = p;
      }
    }
    __syncthreads();  // B2: gates visible; X reads done

    // ---- phase C: act (waves 0,1) / gated_v (waves 4-9) -> ACT ----
    if (w < 2) {
#pragma unroll
      for (int jjb = 0; jjb < 4; ++jjb) {
        const int jb = w * 4 + jjb;  // 0..7
        ux4 p;
#pragma unroll
        for (int r = 0; r < 4; ++r) {
          const float h = acc[jjb][r] * INV;
          p[r] = f2bf(h * sigm(h));
        }
        *(ux4*)(ACT + c16 * LP + jb * 16 + quad * 4) = p;
      }
    } else if (w >= 4) {
      const int vc = (w - 4) >> 1, half = (w - 4) & 1;
      short* gv = ACT + (1 + vc) * TR * LP;
#pragma unroll
      for (int jjb = 0; jjb < 4; ++jjb) {
        const int jb = half * 4 + jjb;  // 0..7 (k-block)
        const ux4 g = *(const ux4*)(GS + c16 * LP + jb * 16 + quad * 4);
        ux4 p;
#pragma unroll
        for (int r = 0; r < 4; ++r)
          p[r] = f2bf(acc[jjb][r] * INV * bf2f(g[r]));
        *(ux4*)(gv + c16 * LP + jb * 16 + quad * 4) = p;
      }
    }
    __syncthreads();  // B3: ACT visible

    // ---- phase D: layer 2 (waves 0-3; g = w), W2 frags from LDS, store ----
    if (w < 4) {
      const short* src = ACT + w * TR * LP;
      const short* wfl = W2L + (w * 4 * 64 + lane) * 8;
      fx4 a = {0.f, 0.f, 0.f, 0.f};
      const int rbase = c16 * LP + mrow0;
#pragma unroll
      for (int kb = 0; kb < 4; ++kb) {
        const bx8 Bf = *(const bx8*)(src + rbase + kb * 32);
        const bx8 Af = *(const bx8*)(wfl + kb * 64 * 8);  // contiguous/lane: conflict-free
        a = __builtin_amdgcn_mfma_f32_16x16x32_bf16(Af, Bf, a, 0, 0, 0);
      }
      const size_t n = (size_t)tile * TR + c16;
      if (w == 0) {
        fx4 o = {a[0] * INV, a[1] * INV, a[2] * INV, a[3] * INV};
        *(fx4*)(out + n * 64 + quad * 4) = o;
      } else {
        const int c = w - 1;
#pragma unroll
        for (int r = 0; r < 4; ++r)
          out[n * 64 + 16 + 3 * (quad * 4 + r) + c] = a[r] * INV;
      }
    }
    // no barrier here: next phase A writes X, disjoint from ACT/GS/W2L reads above;
    // B1 of the next iteration provides the cross-phase sync.
    tile += NBLOCKS;
  }
}

extern "C" void kernel_launch(void* const* d_in, const int* in_sizes, int n_in,
                              void* d_out, int out_size, void* d_ws, size_t ws_size,
                              hipStream_t stream) {
  const float* x    = (const float*)d_in[0];
  const float* w1_s = (const float*)d_in[1];
  const float* w1_v = (const float*)d_in[2];
  const float* w2_s = (const float*)d_in[3];
  const float* w2_v = (const float*)d_in[4];
  nlr_kernel<<<NBLOCKS, NTHREADS, 0, stream>>>(x, w1_s, w1_v, w2_s, w2_v, (float*)d_out);
}